// Round 5
// baseline (1673.603 us; speedup 1.0000x reference)
//
#include <hip/hip_runtime.h>

// GNNCASimple — bf16-MFMA GEMMs (fp32 accumulate), fp32 I/O.
// Per step: p = relu(h@W_pre+b), q = relu(p@W_conv+b)@Wz (Wz=W_post[:256]),
//           zq = segsum(q[src] by dst), h' = zq + p@Wp2 + b_post (Wp2=W_post[256:]).
// CSR built once per launch via bucketed 2-pass counting sort:
//   buckets of 128 nodes; passA scatters (dst,src) to bucket fronts (write-combining
//   friendly); passB does per-node count/scan/scatter in LDS per bucket.

#define NN 100000
#define NPAD 100064   // +64 rows so MFMA fragment loads of the tail block stay in-bounds
#define FS 64
#define HH 256
#define NE 1600000
#define NSTEPS 4
#define BSH 7                      // log2(nodes per bucket)
#define BS (1 << BSH)              // 128 nodes per bucket
#define NBK ((NN + BS - 1) / BS)   // 782 buckets

typedef unsigned short u16;
typedef unsigned int u32;
typedef __attribute__((ext_vector_type(8))) short bfrag;   // 8 bf16 = 4 VGPRs (MFMA A/B)
typedef __attribute__((ext_vector_type(4))) float ffrag;   // 4 fp32 (MFMA C/D)

static __device__ __forceinline__ u16 f2bf(float f) {  // RNE
    union { float f; u32 u; } v; v.f = f;
    return (u16)((v.u + 0x7fffu + ((v.u >> 16) & 1u)) >> 16);
}
static __device__ __forceinline__ float bf2f(u16 h) {
    union { u32 u; float f; } v; v.u = (u32)h << 16; return v.f;
}

// ---------------- x (fp32) -> h (bf16) ----------------
__global__ void cvt_x_k(const float4* __restrict__ x, uint2* __restrict__ hbf, int n4) {
    int i = blockIdx.x * 256 + threadIdx.x;
    if (i < n4) {
        float4 v = x[i];
        uint2 o;
        o.x = (u32)f2bf(v.x) | ((u32)f2bf(v.y) << 16);
        o.y = (u32)f2bf(v.z) | ((u32)f2bf(v.w) << 16);
        hbf[i] = o;
    }
}

// ---------------- W [K][C] fp32 -> Wt [C][K] bf16 ----------------
template <int LK, int LC>
__global__ void transpose_cvt_k(const float* __restrict__ W, u16* __restrict__ Wt) {
    const int K = 1 << LK, C = 1 << LC;
    int i = blockIdx.x * 256 + threadIdx.x;
    if (i < K * C) {
        int c = i >> LK, k = i & (K - 1);
        Wt[i] = f2bf(W[(size_t)k * C + c]);
    }
}

// ---------------- CSR build (bucketed) ----------------
__global__ void zero_int_k(int* __restrict__ p, int n) {
    int i = blockIdx.x * 256 + threadIdx.x;
    if (i < n) p[i] = 0;
}

__global__ void bhist_k(const int* __restrict__ dst, int* __restrict__ bcnt) {
    int e = blockIdx.x * 256 + threadIdx.x;
    if (e < NE) atomicAdd(&bcnt[dst[e] >> BSH], 1);
}

// Single block: exclusive scan of NBK (<=1024) bucket counts -> bstart, bcur, bstart[NBK]=NE.
__global__ void bscan_k(const int* __restrict__ bcnt, int* __restrict__ bstart, int* __restrict__ bcur) {
    __shared__ int sh[256];
    const int t = threadIdx.x;
    const int base = t * 4;
    int v0 = (base + 0 < NBK) ? bcnt[base + 0] : 0;
    int v1 = (base + 1 < NBK) ? bcnt[base + 1] : 0;
    int v2 = (base + 2 < NBK) ? bcnt[base + 2] : 0;
    int v3 = (base + 3 < NBK) ? bcnt[base + 3] : 0;
    int s = v0 + v1 + v2 + v3;
    sh[t] = s;
    __syncthreads();
    for (int o = 1; o < 256; o <<= 1) {
        int y = (t >= o) ? sh[t - o] : 0;
        __syncthreads();
        sh[t] += y;
        __syncthreads();
    }
    int ex = sh[t] - s;
    if (base + 0 < NBK) { bstart[base + 0] = ex; bcur[base + 0] = ex; } ex += v0;
    if (base + 1 < NBK) { bstart[base + 1] = ex; bcur[base + 1] = ex; } ex += v1;
    if (base + 2 < NBK) { bstart[base + 2] = ex; bcur[base + 2] = ex; } ex += v2;
    if (base + 3 < NBK) { bstart[base + 3] = ex; bcur[base + 3] = ex; }
    if (t == 255) bstart[NBK] = sh[255];  // == NE
}

// passA: scatter (dst,src) into bucket-segmented tmp. 782 moving write fronts -> lines fill.
__global__ void passA_k(const int* __restrict__ dst, const int* __restrict__ src,
                        int* __restrict__ bcur, uint2* __restrict__ tmp) {
    int e = blockIdx.x * 256 + threadIdx.x;
    if (e < NE) {
        int d = dst[e];
        int pos = atomicAdd(&bcur[d >> BSH], 1);
        tmp[pos] = make_uint2((u32)d, (u32)src[e]);
    }
}

// passB: one block per bucket. Per-node count/scan in LDS; writes offsets + srcs.
// srcs writes for a bucket land in a contiguous ~8 KB window (cache-resident).
__global__ __launch_bounds__(256) void passB_k(const uint2* __restrict__ tmp,
                                               const int* __restrict__ bstart,
                                               int* __restrict__ offsets,
                                               int* __restrict__ srcs) {
    __shared__ int cnt[BS];
    __shared__ int cur[BS];
    const int t = threadIdx.x;
    const int b = blockIdx.x;
    const int beg = bstart[b], end = bstart[b + 1];
    const int nodeBase = b << BSH;
    if (t < BS) cnt[t] = 0;
    __syncthreads();
    for (int e = beg + t; e < end; e += 256) {
        uint2 ed = tmp[e];
        atomicAdd(&cnt[ed.x - nodeBase], 1);
    }
    __syncthreads();
    int myc = (t < BS) ? cnt[t] : 0;
    for (int o = 1; o < BS; o <<= 1) {   // Hillis-Steele inclusive scan over cnt[0..BS)
        int v = (t >= o && t < BS) ? cnt[t - o] : 0;
        __syncthreads();
        if (t < BS) cnt[t] += v;
        __syncthreads();
    }
    if (t < BS) {
        int excl = beg + cnt[t] - myc;
        cur[t] = excl;
        int node = nodeBase + t;
        if (node < NN) offsets[node] = excl;   // offsets[NN] written by final_off_k
    }
    __syncthreads();
    for (int e = beg + t; e < end; e += 256) {
        uint2 ed = tmp[e];                      // L1/L2-hot re-read
        int pos = atomicAdd(&cur[ed.x - nodeBase], 1);
        srcs[pos] = (int)ed.y;
    }
}

__global__ void final_off_k(int* __restrict__ offsets) {
    if (threadIdx.x == 0) offsets[NN] = NE;
}

// ---------------- pre MLP: p[N,256] = relu(h[N,64] @ W_pre + b_pre), bf16 out ----------------
// 64 nodes/block, 4 waves; wave w owns output cols [64w, 64w+64).
__global__ __launch_bounds__(256) void pre_k(const u16* __restrict__ hbf,   // [NPAD][64]
                                             const u16* __restrict__ Wpt,   // [256][64] (col-major-T)
                                             const float* __restrict__ bias,
                                             u16* __restrict__ pbf) {       // [NPAD][256]
    const int t = threadIdx.x;
    const int wave = t >> 6, lane = t & 63;
    const int quad = lane >> 4, l16 = lane & 15;
    const int nodeBase = blockIdx.x * 64;
    ffrag acc[4][4];
#pragma unroll
    for (int mt = 0; mt < 4; mt++)
#pragma unroll
        for (int nt = 0; nt < 4; nt++) acc[mt][nt] = (ffrag)0.f;

#pragma unroll
    for (int ch = 0; ch < 2; ch++) {
        const int kb = ch * 32 + quad * 8;
        bfrag a[4], b[4];
#pragma unroll
        for (int mt = 0; mt < 4; mt++)
            a[mt] = *(const bfrag*)(hbf + (size_t)(nodeBase + mt * 16 + l16) * FS + kb);
#pragma unroll
        for (int nt = 0; nt < 4; nt++)
            b[nt] = *(const bfrag*)(Wpt + (size_t)(wave * 64 + nt * 16 + l16) * FS + kb);
#pragma unroll
        for (int mt = 0; mt < 4; mt++)
#pragma unroll
            for (int nt = 0; nt < 4; nt++)
                acc[mt][nt] = __builtin_amdgcn_mfma_f32_16x16x32_bf16(a[mt], b[nt], acc[mt][nt], 0, 0, 0);
    }
#pragma unroll
    for (int nt = 0; nt < 4; nt++) {
        const int col = wave * 64 + nt * 16 + l16;
        const float bv = bias[col];
#pragma unroll
        for (int mt = 0; mt < 4; mt++)
#pragma unroll
            for (int r = 0; r < 4; r++) {
                int node = nodeBase + mt * 16 + quad * 4 + r;
                if (node < NN) pbf[(size_t)node * HH + col] = f2bf(fmaxf(acc[mt][nt][r] + bv, 0.f));
            }
    }
}

// ---------------- fused conv: q[N,64] = relu(p @ W_conv + b_conv) @ Wz, bf16 out ----------------
__global__ __launch_bounds__(256) void conv_q_k(const u16* __restrict__ pbf,  // [NPAD][256]
                                                const u16* __restrict__ Wct,  // [256][256]
                                                const float* __restrict__ bc,
                                                const u16* __restrict__ Wzt,  // [64][256]
                                                u16* __restrict__ qbf) {      // [NN][64]
    __shared__ u16 ml[64 * 264];  // m-tile bf16, stride 264 (16B-aligned, conflict-breaking)
    const int t = threadIdx.x;
    const int wave = t >> 6, lane = t & 63;
    const int quad = lane >> 4, l16 = lane & 15;
    const int nodeBase = blockIdx.x * 64;

    // stage 1: m-tile[64][256] = relu(p-tile @ Wc + bc); wave w owns m-cols [64w, 64w+64)
    ffrag acc[4][4];
#pragma unroll
    for (int mt = 0; mt < 4; mt++)
#pragma unroll
        for (int nt = 0; nt < 4; nt++) acc[mt][nt] = (ffrag)0.f;

#pragma unroll
    for (int ch = 0; ch < 8; ch++) {
        const int kb = ch * 32 + quad * 8;
        bfrag a[4], b[4];
#pragma unroll
        for (int mt = 0; mt < 4; mt++)
            a[mt] = *(const bfrag*)(pbf + (size_t)(nodeBase + mt * 16 + l16) * HH + kb);
#pragma unroll
        for (int nt = 0; nt < 4; nt++)
            b[nt] = *(const bfrag*)(Wct + (size_t)(wave * 64 + nt * 16 + l16) * HH + kb);
#pragma unroll
        for (int mt = 0; mt < 4; mt++)
#pragma unroll
            for (int nt = 0; nt < 4; nt++)
                acc[mt][nt] = __builtin_amdgcn_mfma_f32_16x16x32_bf16(a[mt], b[nt], acc[mt][nt], 0, 0, 0);
    }
    // epilogue: bias + relu -> bf16 into LDS
#pragma unroll
    for (int nt = 0; nt < 4; nt++) {
        const int col = wave * 64 + nt * 16 + l16;
        const float bv = bc[col];
#pragma unroll
        for (int mt = 0; mt < 4; mt++)
#pragma unroll
            for (int r = 0; r < 4; r++) {
                int nl = mt * 16 + quad * 4 + r;
                ml[nl * 264 + col] = f2bf(fmaxf(acc[mt][nt][r] + bv, 0.f));
            }
    }
    __syncthreads();

    // stage 2: q-tile[64][64] = m-tile @ Wz; wave w owns q-cols [16w, 16w+16)
    ffrag qa[4];
#pragma unroll
    for (int mt = 0; mt < 4; mt++) qa[mt] = (ffrag)0.f;
#pragma unroll
    for (int ch = 0; ch < 8; ch++) {
        const int kb = ch * 32 + quad * 8;
        bfrag bz = *(const bfrag*)(Wzt + (size_t)(wave * 16 + l16) * HH + kb);
#pragma unroll
        for (int mt = 0; mt < 4; mt++) {
            bfrag am = *(const bfrag*)(ml + (mt * 16 + l16) * 264 + kb);
            qa[mt] = __builtin_amdgcn_mfma_f32_16x16x32_bf16(am, bz, qa[mt], 0, 0, 0);
        }
    }
    const int col = wave * 16 + l16;
#pragma unroll
    for (int mt = 0; mt < 4; mt++)
#pragma unroll
        for (int r = 0; r < 4; r++) {
            int node = nodeBase + mt * 16 + quad * 4 + r;
            if (node < NN) qbf[(size_t)node * FS + col] = f2bf(qa[mt][r]);
        }
}

// ---------------- aggregation: zq[i,:] = sum_{e: dst=i} q[src_e,:] (bf16 q, fp32 zq) ----------------
__global__ __launch_bounds__(256) void agg_k(const u32* __restrict__ q2,  // [NN][32] packed bf16 pairs
                                             const int* __restrict__ offsets,
                                             const int* __restrict__ srcs,
                                             float* __restrict__ zq) {
    const int wave = threadIdx.x >> 6;
    const int lane = threadIdx.x & 63;
    const int node = blockIdx.x * 4 + wave;
    const int half = lane >> 5, c = lane & 31;
    const int beg = offsets[node], end = offsets[node + 1];
    float ax = 0.f, ay = 0.f;
    int e = beg + half;
    for (; e + 2 < end; e += 4) {
        u32 g0 = q2[(size_t)srcs[e] * 32 + c];
        u32 g1 = q2[(size_t)srcs[e + 2] * 32 + c];
        ax += bf2f((u16)g0) + bf2f((u16)g1);
        ay += bf2f((u16)(g0 >> 16)) + bf2f((u16)(g1 >> 16));
    }
    for (; e < end; e += 2) {
        u32 g = q2[(size_t)srcs[e] * 32 + c];
        ax += bf2f((u16)g);
        ay += bf2f((u16)(g >> 16));
    }
    ax += __shfl_xor(ax, 32);
    ay += __shfl_xor(ay, 32);
    if (half == 0) {
        float2 o = make_float2(ax, ay);
        *(float2*)&zq[(size_t)node * FS + 2 * c] = o;
    }
}

// ---------------- post: out[N,64] = zq + p @ Wp2 + b_post ----------------
template <bool LAST>
__global__ __launch_bounds__(256) void post_k(const float* __restrict__ zq,
                                              const u16* __restrict__ pbf,   // [NPAD][256]
                                              const u16* __restrict__ Wp2t,  // [64][256]
                                              const float* __restrict__ bias,
                                              u16* __restrict__ hbf,         // [NPAD][64]
                                              float* __restrict__ outf) {
    const int t = threadIdx.x;
    const int wave = t >> 6, lane = t & 63;
    const int quad = lane >> 4, l16 = lane & 15;
    const int nodeBase = blockIdx.x * 64;
    ffrag acc[4];
#pragma unroll
    for (int mt = 0; mt < 4; mt++) acc[mt] = (ffrag)0.f;

#pragma unroll
    for (int ch = 0; ch < 8; ch++) {
        const int kb = ch * 32 + quad * 8;
        bfrag b = *(const bfrag*)(Wp2t + (size_t)(wave * 16 + l16) * HH + kb);
#pragma unroll
        for (int mt = 0; mt < 4; mt++) {
            bfrag a = *(const bfrag*)(pbf + (size_t)(nodeBase + mt * 16 + l16) * HH + kb);
            acc[mt] = __builtin_amdgcn_mfma_f32_16x16x32_bf16(a, b, acc[mt], 0, 0, 0);
        }
    }
    const int col = wave * 16 + l16;
    const float bv = bias[col];
#pragma unroll
    for (int mt = 0; mt < 4; mt++)
#pragma unroll
        for (int r = 0; r < 4; r++) {
            int node = nodeBase + mt * 16 + quad * 4 + r;
            if (node < NN) {
                float v = acc[mt][r] + zq[(size_t)node * FS + col] + bv;
                if (LAST) outf[(size_t)node * FS + col] = v;
                else      hbf[(size_t)node * FS + col] = f2bf(v);
            }
        }
}

extern "C" void kernel_launch(void* const* d_in, const int* in_sizes, int n_in,
                              void* d_out, int out_size, void* d_ws, size_t ws_size,
                              hipStream_t stream) {
    const float* x      = (const float*)d_in[0];
    const int*   ei     = (const int*)d_in[1];
    const float* W_pre  = (const float*)d_in[2];
    const float* b_pre  = (const float*)d_in[3];
    const float* W_conv = (const float*)d_in[4];
    const float* b_conv = (const float*)d_in[5];
    const float* W_post = (const float*)d_in[6];
    const float* b_post = (const float*)d_in[7];
    float* out = (float*)d_out;

    char* ws = (char*)d_ws;
    size_t off = 0;
    auto alloc = [&](size_t bytes) -> char* {
        char* r = ws + off;
        off += (bytes + 255) & ~(size_t)255;
        return r;
    };
    u16* pbf     = (u16*)alloc((size_t)NPAD * HH * 2);   // 51.2 MB
    u16* hbf     = (u16*)alloc((size_t)NPAD * FS * 2);   // 12.8 MB
    u16* qbf     = (u16*)alloc((size_t)NN * FS * 2);     // 12.8 MB
    float* zq    = (float*)alloc((size_t)NN * FS * 4);   // 25.6 MB
    uint2* tmp   = (uint2*)alloc((size_t)NE * 8);        // 12.8 MB
    int* offsets = (int*)alloc((size_t)(NN + 1) * 4);
    int* srcs    = (int*)alloc((size_t)NE * 4);          //  6.4 MB
    int* bcnt    = (int*)alloc((size_t)NBK * 4);
    int* bstart  = (int*)alloc((size_t)(NBK + 1) * 4);
    int* bcur    = (int*)alloc((size_t)NBK * 4);
    u16* Wpt     = (u16*)alloc((size_t)HH * FS * 2);     // [256][64]
    u16* Wct     = (u16*)alloc((size_t)HH * HH * 2);     // [256][256]
    u16* Wzt     = (u16*)alloc((size_t)FS * HH * 2);     // [64][256]
    u16* Wp2t    = (u16*)alloc((size_t)FS * HH * 2);     // [64][256]
    (void)ws_size; (void)in_sizes; (void)n_in; (void)out_size;

    const int* dst = ei;       // edge_index[0] = aggregation targets
    const int* src = ei + NE;  // edge_index[1] = message sources

    // input casts / weight transposes
    cvt_x_k<<<(NN * FS / 4 + 255) / 256, 256, 0, stream>>>((const float4*)x, (uint2*)hbf, NN * FS / 4);
    transpose_cvt_k<6, 8><<<(HH * FS + 255) / 256, 256, 0, stream>>>(W_pre, Wpt);           // K=64,C=256
    transpose_cvt_k<8, 8><<<(HH * HH + 255) / 256, 256, 0, stream>>>(W_conv, Wct);          // K=256,C=256
    transpose_cvt_k<8, 6><<<(HH * FS + 255) / 256, 256, 0, stream>>>(W_post, Wzt);          // rows [0,256)
    transpose_cvt_k<8, 6><<<(HH * FS + 255) / 256, 256, 0, stream>>>(W_post + HH * FS, Wp2t);  // rows [256,512)

    // CSR build (bucketed 2-pass)
    zero_int_k<<<(NBK + 255) / 256, 256, 0, stream>>>(bcnt, NBK);
    bhist_k<<<(NE + 255) / 256, 256, 0, stream>>>(dst, bcnt);
    bscan_k<<<1, 256, 0, stream>>>(bcnt, bstart, bcur);
    passA_k<<<(NE + 255) / 256, 256, 0, stream>>>(dst, src, bcur, tmp);
    passB_k<<<NBK, 256, 0, stream>>>(tmp, bstart, offsets, srcs);
    final_off_k<<<1, 64, 0, stream>>>(offsets);

    const int GB = (NN + 63) / 64;  // 1563
    for (int s = 0; s < NSTEPS; s++) {
        pre_k<<<GB, 256, 0, stream>>>(hbf, Wpt, b_pre, pbf);
        conv_q_k<<<GB, 256, 0, stream>>>(pbf, Wct, b_conv, Wzt, qbf);
        agg_k<<<NN / 4, 256, 0, stream>>>((const u32*)qbf, offsets, srcs, zq);
        if (s < NSTEPS - 1)
            post_k<false><<<GB, 256, 0, stream>>>(zq, pbf, Wp2t, b_post, hbf, nullptr);
        else
            post_k<true><<<GB, 256, 0, stream>>>(zq, pbf, Wp2t, b_post, nullptr, out);
    }
}

// Round 6
// 797.467 us; speedup vs baseline: 2.0986x; 2.0986x over previous
//
#include <hip/hip_runtime.h>

// GNNCASimple — fused per-node pipeline (bf16 MFMA, fp32 accum), fp32 I/O.
// Step s: h = zq_{s-1} + pw2_{s-1} + b_post (or x at s=0)
//         p = relu(h@W_pre+b_pre)        [LDS only]
//         m = relu(p@W_conv+b_conv)      [LDS only]
//         q = m@Wz,  pw2 = p@Wp2         (Wz=W_post[:256], Wp2=W_post[256:])
//         zq = segsum(q[src] by dst)
// Final: out = zq + pw2 + b_post.
// CSR: round-3 counting sort (100k cursors — round-4's 782-bucket variant hit
// atomic contention: 2046 collisions/cursor, 377 us; 100k cursors = 16/cursor).

#define NN 100000
#define NPAD 100064   // +64 rows so tail-tile vector reads stay inside the allocation
#define FS 64
#define HH 256
#define NE 1600000
#define NSTEPS 4

typedef unsigned short u16;
typedef unsigned int u32;
typedef __attribute__((ext_vector_type(8))) short bfrag;   // 8 bf16 = 4 VGPRs (MFMA A/B)
typedef __attribute__((ext_vector_type(4))) float ffrag;   // 4 fp32 (MFMA C/D)

static __device__ __forceinline__ u16 f2bf(float f) {  // RNE
    union { float f; u32 u; } v; v.f = f;
    return (u16)((v.u + 0x7fffu + ((v.u >> 16) & 1u)) >> 16);
}
static __device__ __forceinline__ float bf2f(u16 h) {
    union { u32 u; float f; } v; v.u = (u32)h << 16; return v.f;
}
static __device__ __forceinline__ u32 pack2bf(float a, float b) {
    return (u32)f2bf(a) | ((u32)f2bf(b) << 16);
}

// ---------------- x (fp32) -> hbf (bf16) ----------------
__global__ void cvt_x_k(const float4* __restrict__ x, uint2* __restrict__ hbf, int n4) {
    int i = blockIdx.x * 256 + threadIdx.x;
    if (i < n4) {
        float4 v = x[i];
        hbf[i] = make_uint2(pack2bf(v.x, v.y), pack2bf(v.z, v.w));
    }
}

// ---------------- W [K][C] fp32 -> Wt [C][K] bf16 ----------------
template <int LK, int LC>
__global__ void transpose_cvt_k(const float* __restrict__ W, u16* __restrict__ Wt) {
    const int K = 1 << LK, C = 1 << LC;
    int i = blockIdx.x * 256 + threadIdx.x;
    if (i < K * C) {
        int c = i >> LK, k = i & (K - 1);
        Wt[i] = f2bf(W[(size_t)k * C + c]);
    }
}

// ---------------- CSR build (round-3 counting sort) ----------------
__global__ void zero_int_k(int* __restrict__ p, int n) {
    int i = blockIdx.x * 256 + threadIdx.x;
    if (i < n) p[i] = 0;
}

__global__ void hist_k(const int* __restrict__ dst, int* __restrict__ cnt) {
    int e = blockIdx.x * 256 + threadIdx.x;
    if (e < NE) atomicAdd(&cnt[dst[e]], 1);
}

__global__ void scan1_k(const int* __restrict__ cnt, int* __restrict__ part, int* __restrict__ sums) {
    __shared__ int sh[256];
    const int t = threadIdx.x;
    const int base = blockIdx.x * 1024 + t * 4;
    int v0 = (base + 0 < NN) ? cnt[base + 0] : 0;
    int v1 = (base + 1 < NN) ? cnt[base + 1] : 0;
    int v2 = (base + 2 < NN) ? cnt[base + 2] : 0;
    int v3 = (base + 3 < NN) ? cnt[base + 3] : 0;
    int s = v0 + v1 + v2 + v3;
    sh[t] = s;
    __syncthreads();
    for (int o = 1; o < 256; o <<= 1) {
        int y = (t >= o) ? sh[t - o] : 0;
        __syncthreads();
        sh[t] += y;
        __syncthreads();
    }
    int ex = sh[t] - s;
    if (base + 0 < NN) part[base + 0] = ex; ex += v0;
    if (base + 1 < NN) part[base + 1] = ex; ex += v1;
    if (base + 2 < NN) part[base + 2] = ex; ex += v2;
    if (base + 3 < NN) part[base + 3] = ex;
    if (t == 0) sums[blockIdx.x] = sh[255];
}

__global__ void scan2_k(int* __restrict__ sums, int nb, int* __restrict__ total_out) {
    __shared__ int sh[128];
    const int t = threadIdx.x;
    int v = (t < nb) ? sums[t] : 0;
    sh[t] = v;
    __syncthreads();
    for (int o = 1; o < 128; o <<= 1) {
        int y = (t >= o) ? sh[t - o] : 0;
        __syncthreads();
        sh[t] += y;
        __syncthreads();
    }
    if (t < nb) sums[t] = sh[t] - v;
    if (t == 0) *total_out = sh[127];
}

__global__ void scan3_k(int* __restrict__ part, const int* __restrict__ sums, int* __restrict__ cursor) {
    int i = blockIdx.x * 256 + threadIdx.x;
    if (i < NN) {
        int v = part[i] + sums[i >> 10];
        part[i] = v;
        cursor[i] = v;
    }
}

__global__ void fill_k(const int* __restrict__ dst, const int* __restrict__ src,
                       int* __restrict__ cursor, int* __restrict__ srcs) {
    int e = blockIdx.x * 256 + threadIdx.x;
    if (e < NE) {
        int d = dst[e];
        int pos = atomicAdd(&cursor[d], 1);
        srcs[pos] = src[e];
    }
}

// ---------------- fused node transform ----------------
// Per 64-node tile: h (from x or zq+pw2+b_post) -> p -> m -> {q, pw2}.
// 256 threads = 4 waves. LDS: hs 9.2KB + ps 33.8KB + ms 33.8KB = 77KB (2 blocks/CU).
template <bool FIRST>
__global__ __launch_bounds__(256) void xform_k(const u16* __restrict__ hbf,     // [NPAD][64] (FIRST)
                                               const float* __restrict__ zq,    // [NPAD][64]
                                               const float* __restrict__ pw2i,  // [NPAD][64]
                                               const float* __restrict__ b_post,
                                               const u16* __restrict__ Wpt,     // [256][64]
                                               const float* __restrict__ b_pre,
                                               const u16* __restrict__ Wct,     // [256][256]
                                               const float* __restrict__ b_conv,
                                               const u16* __restrict__ Wzt,     // [64][256]
                                               const u16* __restrict__ Wp2t,    // [64][256]
                                               u16* __restrict__ qbf,           // [NN][64]
                                               float* __restrict__ pw2o) {      // [NPAD][64]
    __shared__ u16 hs[64 * 72];    // h tile bf16, stride 72 (144 B rows, 16B-aligned)
    __shared__ u16 ps[64 * 264];   // p tile bf16
    __shared__ u16 ms[64 * 264];   // m tile bf16
    const int t = threadIdx.x;
    const int wave = t >> 6, lane = t & 63;
    const int quad = lane >> 4, l16 = lane & 15;
    const int nodeBase = blockIdx.x * 64;

    // ---- stage 0: build h tile in LDS ----
    {
        const int nn = t >> 2;             // 0..63
        const int c0 = (t & 3) * 16;       // 0,16,32,48
        const size_t node = (size_t)(nodeBase + nn);
        if (FIRST) {
            uint4* d = (uint4*)(hs + nn * 72 + c0);
            const uint4* s = (const uint4*)(hbf + node * FS + c0);
            d[0] = s[0];
            d[1] = s[1];
        } else {
            const float4* zp = (const float4*)(zq + node * FS + c0);
            const float4* pp = (const float4*)(pw2i + node * FS + c0);
            const float4* bp = (const float4*)(b_post + c0);
            u32* d = (u32*)(hs + nn * 72 + c0);
#pragma unroll
            for (int i = 0; i < 4; i++) {
                float4 z = zp[i], p = pp[i], b = bp[i];
                d[2 * i + 0] = pack2bf(z.x + p.x + b.x, z.y + p.y + b.y);
                d[2 * i + 1] = pack2bf(z.z + p.z + b.z, z.w + p.w + b.w);
            }
        }
    }
    __syncthreads();

    // ---- stage 1: p = relu(h @ W_pre + b_pre); wave w owns p-cols [64w, 64w+64) ----
    {
        ffrag acc[4][4];
#pragma unroll
        for (int mt = 0; mt < 4; mt++)
#pragma unroll
            for (int nt = 0; nt < 4; nt++) acc[mt][nt] = (ffrag)0.f;
#pragma unroll
        for (int ch = 0; ch < 2; ch++) {
            const int kb = ch * 32 + quad * 8;
            bfrag a[4], b[4];
#pragma unroll
            for (int mt = 0; mt < 4; mt++)
                a[mt] = *(const bfrag*)(hs + (mt * 16 + l16) * 72 + kb);
#pragma unroll
            for (int nt = 0; nt < 4; nt++)
                b[nt] = *(const bfrag*)(Wpt + (size_t)(wave * 64 + nt * 16 + l16) * FS + kb);
#pragma unroll
            for (int mt = 0; mt < 4; mt++)
#pragma unroll
                for (int nt = 0; nt < 4; nt++)
                    acc[mt][nt] = __builtin_amdgcn_mfma_f32_16x16x32_bf16(a[mt], b[nt], acc[mt][nt], 0, 0, 0);
        }
#pragma unroll
        for (int nt = 0; nt < 4; nt++) {
            const int col = wave * 64 + nt * 16 + l16;
            const float bv = b_pre[col];
#pragma unroll
            for (int mt = 0; mt < 4; mt++)
#pragma unroll
                for (int r = 0; r < 4; r++)
                    ps[(mt * 16 + quad * 4 + r) * 264 + col] = f2bf(fmaxf(acc[mt][nt][r] + bv, 0.f));
        }
    }
    __syncthreads();

    // ---- stage 2: m = relu(p @ W_conv + b_conv); wave w owns m-cols [64w, 64w+64) ----
    {
        ffrag acc[4][4];
#pragma unroll
        for (int mt = 0; mt < 4; mt++)
#pragma unroll
            for (int nt = 0; nt < 4; nt++) acc[mt][nt] = (ffrag)0.f;
#pragma unroll
        for (int ch = 0; ch < 8; ch++) {
            const int kb = ch * 32 + quad * 8;
            bfrag a[4], b[4];
#pragma unroll
            for (int mt = 0; mt < 4; mt++)
                a[mt] = *(const bfrag*)(ps + (mt * 16 + l16) * 264 + kb);
#pragma unroll
            for (int nt = 0; nt < 4; nt++)
                b[nt] = *(const bfrag*)(Wct + (size_t)(wave * 64 + nt * 16 + l16) * HH + kb);
#pragma unroll
            for (int mt = 0; mt < 4; mt++)
#pragma unroll
                for (int nt = 0; nt < 4; nt++)
                    acc[mt][nt] = __builtin_amdgcn_mfma_f32_16x16x32_bf16(a[mt], b[nt], acc[mt][nt], 0, 0, 0);
        }
#pragma unroll
        for (int nt = 0; nt < 4; nt++) {
            const int col = wave * 64 + nt * 16 + l16;
            const float bv = b_conv[col];
#pragma unroll
            for (int mt = 0; mt < 4; mt++)
#pragma unroll
                for (int r = 0; r < 4; r++)
                    ms[(mt * 16 + quad * 4 + r) * 264 + col] = f2bf(fmaxf(acc[mt][nt][r] + bv, 0.f));
        }
    }
    __syncthreads();

    // ---- stage 3: q = m @ Wz (bf16 out), pw2 = p @ Wp2 (fp32 out); wave w owns cols [16w,16w+16) ----
    {
        ffrag qa[4], wa[4];
#pragma unroll
        for (int mt = 0; mt < 4; mt++) { qa[mt] = (ffrag)0.f; wa[mt] = (ffrag)0.f; }
#pragma unroll
        for (int ch = 0; ch < 8; ch++) {
            const int kb = ch * 32 + quad * 8;
            bfrag bz = *(const bfrag*)(Wzt + (size_t)(wave * 16 + l16) * HH + kb);
            bfrag bw = *(const bfrag*)(Wp2t + (size_t)(wave * 16 + l16) * HH + kb);
#pragma unroll
            for (int mt = 0; mt < 4; mt++) {
                bfrag am = *(const bfrag*)(ms + (mt * 16 + l16) * 264 + kb);
                bfrag ap = *(const bfrag*)(ps + (mt * 16 + l16) * 264 + kb);
                qa[mt] = __builtin_amdgcn_mfma_f32_16x16x32_bf16(am, bz, qa[mt], 0, 0, 0);
                wa[mt] = __builtin_amdgcn_mfma_f32_16x16x32_bf16(ap, bw, wa[mt], 0, 0, 0);
            }
        }
        const int col = wave * 16 + l16;
#pragma unroll
        for (int mt = 0; mt < 4; mt++)
#pragma unroll
            for (int r = 0; r < 4; r++) {
                int node = nodeBase + mt * 16 + quad * 4 + r;
                if (node < NN) {
                    qbf[(size_t)node * FS + col] = f2bf(qa[mt][r]);
                    pw2o[(size_t)node * FS + col] = wa[mt][r];
                }
            }
    }
}

// ---------------- aggregation: zq[i,:] = sum_{e: dst=i} q[src_e,:] (bf16 q, fp32 zq) ----------------
__global__ __launch_bounds__(256) void agg_k(const u32* __restrict__ q2,  // [NN][32] packed bf16 pairs
                                             const int* __restrict__ offsets,
                                             const int* __restrict__ srcs,
                                             float* __restrict__ zq) {
    const int wave = threadIdx.x >> 6;
    const int lane = threadIdx.x & 63;
    const int node = blockIdx.x * 4 + wave;
    const int half = lane >> 5, c = lane & 31;
    const int beg = offsets[node], end = offsets[node + 1];
    float ax = 0.f, ay = 0.f;
    int e = beg + half;
    for (; e + 2 < end; e += 4) {
        u32 g0 = q2[(size_t)srcs[e] * 32 + c];
        u32 g1 = q2[(size_t)srcs[e + 2] * 32 + c];
        ax += bf2f((u16)g0) + bf2f((u16)g1);
        ay += bf2f((u16)(g0 >> 16)) + bf2f((u16)(g1 >> 16));
    }
    for (; e < end; e += 2) {
        u32 g = q2[(size_t)srcs[e] * 32 + c];
        ax += bf2f((u16)g);
        ay += bf2f((u16)(g >> 16));
    }
    ax += __shfl_xor(ax, 32);
    ay += __shfl_xor(ay, 32);
    if (half == 0) {
        *(float2*)&zq[(size_t)node * FS + 2 * c] = make_float2(ax, ay);
    }
}

// ---------------- final: out = zq + pw2 + b_post (fp32 elementwise) ----------------
__global__ void final_out_k(const float4* __restrict__ zq, const float4* __restrict__ pw2,
                            const float* __restrict__ b_post, float4* __restrict__ out, int n4) {
    int i = blockIdx.x * 256 + threadIdx.x;
    if (i < n4) {
        float4 z = zq[i], p = pw2[i];
        const float4 b = *(const float4*)(b_post + (i & 15) * 4);
        out[i] = make_float4(z.x + p.x + b.x, z.y + p.y + b.y, z.z + p.z + b.z, z.w + p.w + b.w);
    }
}

extern "C" void kernel_launch(void* const* d_in, const int* in_sizes, int n_in,
                              void* d_out, int out_size, void* d_ws, size_t ws_size,
                              hipStream_t stream) {
    const float* x      = (const float*)d_in[0];
    const int*   ei     = (const int*)d_in[1];
    const float* W_pre  = (const float*)d_in[2];
    const float* b_pre  = (const float*)d_in[3];
    const float* W_conv = (const float*)d_in[4];
    const float* b_conv = (const float*)d_in[5];
    const float* W_post = (const float*)d_in[6];
    const float* b_post = (const float*)d_in[7];
    float* out = (float*)d_out;

    char* ws = (char*)d_ws;
    size_t off = 0;
    auto alloc = [&](size_t bytes) -> char* {
        char* r = ws + off;
        off += (bytes + 255) & ~(size_t)255;
        return r;
    };
    u16* hbf     = (u16*)alloc((size_t)NPAD * FS * 2);    // 12.8 MB
    u16* qbf     = (u16*)alloc((size_t)NN * FS * 2);      // 12.8 MB
    float* zq    = (float*)alloc((size_t)NPAD * FS * 4);  // 25.6 MB
    float* pw2   = (float*)alloc((size_t)NPAD * FS * 4);  // 25.6 MB
    int* offsets = (int*)alloc((size_t)(NN + 1) * 4);
    int* cursor  = (int*)alloc((size_t)NN * 4);
    int* srcs    = (int*)alloc((size_t)NE * 4);           //  6.4 MB
    int* sums    = (int*)alloc(128 * 4);
    u16* Wpt     = (u16*)alloc((size_t)HH * FS * 2);      // [256][64]
    u16* Wct     = (u16*)alloc((size_t)HH * HH * 2);      // [256][256]
    u16* Wzt     = (u16*)alloc((size_t)FS * HH * 2);      // [64][256]
    u16* Wp2t    = (u16*)alloc((size_t)FS * HH * 2);      // [64][256]
    (void)ws_size; (void)in_sizes; (void)n_in; (void)out_size;

    const int* dst = ei;       // edge_index[0] = aggregation targets
    const int* src = ei + NE;  // edge_index[1] = message sources

    // input casts / weight transposes
    cvt_x_k<<<(NN * FS / 4 + 255) / 256, 256, 0, stream>>>((const float4*)x, (uint2*)hbf, NN * FS / 4);
    transpose_cvt_k<6, 8><<<(HH * FS + 255) / 256, 256, 0, stream>>>(W_pre, Wpt);
    transpose_cvt_k<8, 8><<<(HH * HH + 255) / 256, 256, 0, stream>>>(W_conv, Wct);
    transpose_cvt_k<8, 6><<<(HH * FS + 255) / 256, 256, 0, stream>>>(W_post, Wzt);
    transpose_cvt_k<8, 6><<<(HH * FS + 255) / 256, 256, 0, stream>>>(W_post + HH * FS, Wp2t);

    // CSR build (round-3 counting sort)
    zero_int_k<<<(NN + 255) / 256, 256, 0, stream>>>(cursor, NN);
    hist_k<<<(NE + 255) / 256, 256, 0, stream>>>(dst, cursor);
    const int NB = (NN + 1023) / 1024;  // 98
    scan1_k<<<NB, 256, 0, stream>>>(cursor, offsets, sums);
    scan2_k<<<1, 128, 0, stream>>>(sums, NB, offsets + NN);
    scan3_k<<<(NN + 255) / 256, 256, 0, stream>>>(offsets, sums, cursor);
    fill_k<<<(NE + 255) / 256, 256, 0, stream>>>(dst, src, cursor, srcs);

    const int GB = (NN + 63) / 64;  // 1563
    for (int s = 0; s < NSTEPS; s++) {
        if (s == 0)
            xform_k<true><<<GB, 256, 0, stream>>>(hbf, nullptr, nullptr, b_post,
                                                  Wpt, b_pre, Wct, b_conv, Wzt, Wp2t, qbf, pw2);
        else
            xform_k<false><<<GB, 256, 0, stream>>>(nullptr, zq, pw2, b_post,
                                                   Wpt, b_pre, Wct, b_conv, Wzt, Wp2t, qbf, pw2);
        agg_k<<<NN / 4, 256, 0, stream>>>((const u32*)qbf, offsets, srcs, zq);
    }
    final_out_k<<<(NN * 16 + 255) / 256, 256, 0, stream>>>((const float4*)zq, (const float4*)pw2,
                                                           b_post, (float4*)out, NN * 16);
}

// Round 7
// 774.004 us; speedup vs baseline: 2.1623x; 1.0303x over previous
//
#include <hip/hip_runtime.h>

// GNNCASimple — fused per-node pipeline (bf16 MFMA, fp32 accum), fp32 I/O.
// Step s: h = zq_{s-1} + pw2_{s-1} + b_post (or x at s=0)   [built in regs]
//         p = relu(h@W_pre+b_pre)        [LDS only]
//         m = relu(p@W_conv+b_conv)      [LDS only]
//         q = m@Wz,  pw2 = p@Wp2         (Wz=W_post[:256], Wp2=W_post[256:])
//         zq = segsum(q[src] by dst)
// Final: out = zq + pw2 + b_post.
// CSR: hist+scan for offsets; srcs permutation via two-phase local-group scatter
// (fill_k's 4B random scatter cost 130us/106MB writes from L2 line thrash; return-
//  atomics on few addresses serialize at ~184ns — so: LDS-binned private segments).

#define NN 100000
#define NPAD 100064   // +64 rows so tail-tile vector reads stay inside the allocation
#define FS 64
#define HH 256
#define NE 1600000
#define NSTEPS 4
#define GA 128                    // fillA blocks
#define EPB (NE / GA)             // 12500 edges per fillA block
#define BK2SH 9                   // log2(nodes per coarse bucket)
#define NBK2 ((NN + 511) / 512)   // 196 buckets

typedef unsigned short u16;
typedef unsigned int u32;
typedef __attribute__((ext_vector_type(8))) short bfrag;   // 8 bf16 = 4 VGPRs (MFMA A/B)
typedef __attribute__((ext_vector_type(4))) float ffrag;   // 4 fp32 (MFMA C/D)

static __device__ __forceinline__ float4 ld4(const float* p) { return *(const float4*)p; }
static __device__ __forceinline__ u16 f2bf(float f) {  // RNE
    union { float f; u32 u; } v; v.f = f;
    return (u16)((v.u + 0x7fffu + ((v.u >> 16) & 1u)) >> 16);
}
static __device__ __forceinline__ float bf2f(u16 h) {
    union { u32 u; float f; } v; v.u = (u32)h << 16; return v.f;
}
static __device__ __forceinline__ u32 pack2bf(float a, float b) {
    return (u32)f2bf(a) | ((u32)f2bf(b) << 16);
}

// ---------------- x (fp32) -> hbf (bf16) ----------------
__global__ void cvt_x_k(const float4* __restrict__ x, uint2* __restrict__ hbf, int n4) {
    int i = blockIdx.x * 256 + threadIdx.x;
    if (i < n4) {
        float4 v = x[i];
        hbf[i] = make_uint2(pack2bf(v.x, v.y), pack2bf(v.z, v.w));
    }
}

// ---------------- W [K][C] fp32 -> Wt [C][K] bf16 ----------------
template <int LK, int LC>
__global__ void transpose_cvt_k(const float* __restrict__ W, u16* __restrict__ Wt) {
    const int K = 1 << LK, C = 1 << LC;
    int i = blockIdx.x * 256 + threadIdx.x;
    if (i < K * C) {
        int c = i >> LK, k = i & (K - 1);
        Wt[i] = f2bf(W[(size_t)k * C + c]);
    }
}

// ---------------- offsets: per-node histogram + scan ----------------
__global__ void zero_int_k(int* __restrict__ p, int n) {
    int i = blockIdx.x * 256 + threadIdx.x;
    if (i < n) p[i] = 0;
}

__global__ void hist_k(const int* __restrict__ dst, int* __restrict__ cnt) {
    int e = blockIdx.x * 256 + threadIdx.x;
    if (e < NE) atomicAdd(&cnt[dst[e]], 1);   // no-return atomics: cheap (r4/r5 evidence)
}

__global__ void scan1_k(const int* __restrict__ cnt, int* __restrict__ part, int* __restrict__ sums) {
    __shared__ int sh[256];
    const int t = threadIdx.x;
    const int base = blockIdx.x * 1024 + t * 4;
    int v0 = (base + 0 < NN) ? cnt[base + 0] : 0;
    int v1 = (base + 1 < NN) ? cnt[base + 1] : 0;
    int v2 = (base + 2 < NN) ? cnt[base + 2] : 0;
    int v3 = (base + 3 < NN) ? cnt[base + 3] : 0;
    int s = v0 + v1 + v2 + v3;
    sh[t] = s;
    __syncthreads();
    for (int o = 1; o < 256; o <<= 1) {
        int y = (t >= o) ? sh[t - o] : 0;
        __syncthreads();
        sh[t] += y;
        __syncthreads();
    }
    int ex = sh[t] - s;
    if (base + 0 < NN) part[base + 0] = ex; ex += v0;
    if (base + 1 < NN) part[base + 1] = ex; ex += v1;
    if (base + 2 < NN) part[base + 2] = ex; ex += v2;
    if (base + 3 < NN) part[base + 3] = ex;
    if (t == 0) sums[blockIdx.x] = sh[255];
}

__global__ void scan2_k(int* __restrict__ sums, int nb) {
    __shared__ int sh[128];
    const int t = threadIdx.x;
    int v = (t < nb) ? sums[t] : 0;
    sh[t] = v;
    __syncthreads();
    for (int o = 1; o < 128; o <<= 1) {
        int y = (t >= o) ? sh[t - o] : 0;
        __syncthreads();
        sh[t] += y;
        __syncthreads();
    }
    if (t < nb) sums[t] = sh[t] - v;
}

__global__ void scan3_k(int* __restrict__ offsets, const int* __restrict__ sums) {
    int i = blockIdx.x * 256 + threadIdx.x;
    if (i < NN) offsets[i] += sums[i >> 10];
    if (i == NN) {}  // offsets[NN] set by final_off_k
}

__global__ void final_off_k(int* __restrict__ offsets) {
    if (threadIdx.x == 0) offsets[NN] = NE;
}

// ---------------- fillA: group edges into per-block private segments by coarse bucket ----------------
__global__ __launch_bounds__(256) void fillA_k(const int* __restrict__ dst, const int* __restrict__ src,
                                               int* __restrict__ cntM, int* __restrict__ offM,  // [NBK2][GA]
                                               uint2* __restrict__ tmp) {
    __shared__ int cnt[256];
    __shared__ int sc[256];
    __shared__ int cur[256];
    const int t = threadIdx.x, b = blockIdx.x;
    const int e0 = b * EPB;
    cnt[t] = 0;
    __syncthreads();
    for (int i = t; i < EPB; i += 256) atomicAdd(&cnt[dst[e0 + i] >> BK2SH], 1);
    __syncthreads();
    int v = cnt[t];
    sc[t] = v;
    __syncthreads();
    for (int o = 1; o < 256; o <<= 1) {
        int y = (t >= o) ? sc[t - o] : 0;
        __syncthreads();
        sc[t] += y;
        __syncthreads();
    }
    int excl = sc[t] - v;
    cur[t] = excl;
    if (t < NBK2) {
        cntM[t * GA + b] = v;
        offM[t * GA + b] = excl;
    }
    __syncthreads();
    uint2* seg = tmp + (size_t)b * EPB;
    for (int i = t; i < EPB; i += 256) {
        int d = dst[e0 + i], s = src[e0 + i];
        int pos = atomicAdd(&cur[d >> BK2SH], 1);
        seg[pos] = make_uint2((u32)d, (u32)s);
    }
}

// ---------------- fillB: one block per bucket; scatter srcs into contiguous window ----------------
__global__ __launch_bounds__(256) void fillB_k(const uint2* __restrict__ tmp,
                                               const int* __restrict__ cntM, const int* __restrict__ offM,
                                               const int* __restrict__ offsets, int* __restrict__ srcs) {
    __shared__ int cur[512];
    __shared__ int runlen[GA];
    __shared__ int runoff[GA];
    const int t = threadIdx.x, k = blockIdx.x;
    const int nodeBase = k << BK2SH;
    for (int i = t; i < 512; i += 256) {
        int node = nodeBase + i;
        cur[i] = (node < NN) ? offsets[node] : 0;
    }
    if (t < GA) {
        runlen[t] = cntM[k * GA + t];
        runoff[t] = offM[k * GA + t];
    }
    __syncthreads();
    const int rsub = t >> 6;     // 4 runs processed concurrently (one per wave)
    const int elane = t & 63;
    for (int g = 0; g < GA / 4; g++) {
        int rb = g * 4 + rsub;
        int len = runlen[rb];
        const uint2* run = tmp + (size_t)rb * EPB + runoff[rb];
        for (int e = elane; e < len; e += 64) {
            uint2 ed = run[e];
            int pos = atomicAdd(&cur[(int)ed.x - nodeBase], 1);
            srcs[pos] = (int)ed.y;
        }
    }
}

// ---------------- fused node transform ----------------
// Per 64-node tile: h (regs, from x or zq+pw2+b_post) -> p (LDS) -> m (LDS) -> {q, pw2}.
// 256 threads = 4 waves. LDS: ps 33.8KB + ms 33.8KB = 67.6KB (2 blocks/CU).
template <bool FIRST>
__global__ __launch_bounds__(256) void xform_k(const u16* __restrict__ hbf,     // [NPAD][64] (FIRST)
                                               const float* __restrict__ zq,    // [NPAD][64]
                                               const float* __restrict__ pw2i,  // [NPAD][64]
                                               const float* __restrict__ b_post,
                                               const u16* __restrict__ Wpt,     // [256][64]
                                               const float* __restrict__ b_pre,
                                               const u16* __restrict__ Wct,     // [256][256]
                                               const float* __restrict__ b_conv,
                                               const u16* __restrict__ Wzt,     // [64][256]
                                               const u16* __restrict__ Wp2t,    // [64][256]
                                               u16* __restrict__ qbf,           // [NN][64]
                                               float* __restrict__ pw2o) {      // [NPAD][64]
    __shared__ u16 ps[64 * 264];   // p tile bf16
    __shared__ u16 ms[64 * 264];   // m tile bf16
    const int t = threadIdx.x;
    const int wave = t >> 6, lane = t & 63;
    const int quad = lane >> 4, l16 = lane & 15;
    const int nodeBase = blockIdx.x * 64;

    // ---- stage 1: p = relu(h @ W_pre + b_pre); wave w owns p-cols [64w, 64w+64) ----
    {
        ffrag acc[4][4];
#pragma unroll
        for (int mt = 0; mt < 4; mt++)
#pragma unroll
            for (int nt = 0; nt < 4; nt++) acc[mt][nt] = (ffrag)0.f;
#pragma unroll
        for (int ch = 0; ch < 2; ch++) {
            const int kb = ch * 32 + quad * 8;
            bfrag a[4], b[4];
#pragma unroll
            for (int mt = 0; mt < 4; mt++) {
                const size_t node = (size_t)(nodeBase + mt * 16 + l16);
                if (FIRST) {
                    a[mt] = *(const bfrag*)(hbf + node * FS + kb);
                } else {
                    const float* zr = zq + node * FS + kb;
                    const float* pr = pw2i + node * FS + kb;
                    float4 z0 = ld4(zr), z1 = ld4(zr + 4);
                    float4 p0 = ld4(pr), p1 = ld4(pr + 4);
                    float4 b0 = ld4(b_post + kb), b1 = ld4(b_post + kb + 4);
                    union { bfrag v; u32 w[4]; } u;
                    u.w[0] = pack2bf(z0.x + p0.x + b0.x, z0.y + p0.y + b0.y);
                    u.w[1] = pack2bf(z0.z + p0.z + b0.z, z0.w + p0.w + b0.w);
                    u.w[2] = pack2bf(z1.x + p1.x + b1.x, z1.y + p1.y + b1.y);
                    u.w[3] = pack2bf(z1.z + p1.z + b1.z, z1.w + p1.w + b1.w);
                    a[mt] = u.v;
                }
            }
#pragma unroll
            for (int nt = 0; nt < 4; nt++)
                b[nt] = *(const bfrag*)(Wpt + (size_t)(wave * 64 + nt * 16 + l16) * FS + kb);
#pragma unroll
            for (int mt = 0; mt < 4; mt++)
#pragma unroll
                for (int nt = 0; nt < 4; nt++)
                    acc[mt][nt] = __builtin_amdgcn_mfma_f32_16x16x32_bf16(a[mt], b[nt], acc[mt][nt], 0, 0, 0);
        }
#pragma unroll
        for (int nt = 0; nt < 4; nt++) {
            const int col = wave * 64 + nt * 16 + l16;
            const float bv = b_pre[col];
#pragma unroll
            for (int mt = 0; mt < 4; mt++)
#pragma unroll
                for (int r = 0; r < 4; r++)
                    ps[(mt * 16 + quad * 4 + r) * 264 + col] = f2bf(fmaxf(acc[mt][nt][r] + bv, 0.f));
        }
    }
    __syncthreads();

    // ---- stage 2: m = relu(p @ W_conv + b_conv); wave w owns m-cols [64w, 64w+64) ----
    {
        ffrag acc[4][4];
#pragma unroll
        for (int mt = 0; mt < 4; mt++)
#pragma unroll
            for (int nt = 0; nt < 4; nt++) acc[mt][nt] = (ffrag)0.f;
#pragma unroll
        for (int ch = 0; ch < 8; ch++) {
            const int kb = ch * 32 + quad * 8;
            bfrag a[4], b[4];
#pragma unroll
            for (int mt = 0; mt < 4; mt++)
                a[mt] = *(const bfrag*)(ps + (mt * 16 + l16) * 264 + kb);
#pragma unroll
            for (int nt = 0; nt < 4; nt++)
                b[nt] = *(const bfrag*)(Wct + (size_t)(wave * 64 + nt * 16 + l16) * HH + kb);
#pragma unroll
            for (int mt = 0; mt < 4; mt++)
#pragma unroll
                for (int nt = 0; nt < 4; nt++)
                    acc[mt][nt] = __builtin_amdgcn_mfma_f32_16x16x32_bf16(a[mt], b[nt], acc[mt][nt], 0, 0, 0);
        }
#pragma unroll
        for (int nt = 0; nt < 4; nt++) {
            const int col = wave * 64 + nt * 16 + l16;
            const float bv = b_conv[col];
#pragma unroll
            for (int mt = 0; mt < 4; mt++)
#pragma unroll
                for (int r = 0; r < 4; r++)
                    ms[(mt * 16 + quad * 4 + r) * 264 + col] = f2bf(fmaxf(acc[mt][nt][r] + bv, 0.f));
        }
    }
    __syncthreads();

    // ---- stage 3: q = m @ Wz (bf16 out), pw2 = p @ Wp2 (fp32 out); wave w owns cols [16w,16w+16) ----
    {
        ffrag qa[4], wa[4];
#pragma unroll
        for (int mt = 0; mt < 4; mt++) { qa[mt] = (ffrag)0.f; wa[mt] = (ffrag)0.f; }
#pragma unroll
        for (int ch = 0; ch < 8; ch++) {
            const int kb = ch * 32 + quad * 8;
            bfrag bz = *(const bfrag*)(Wzt + (size_t)(wave * 16 + l16) * HH + kb);
            bfrag bw = *(const bfrag*)(Wp2t + (size_t)(wave * 16 + l16) * HH + kb);
#pragma unroll
            for (int mt = 0; mt < 4; mt++) {
                bfrag am = *(const bfrag*)(ms + (mt * 16 + l16) * 264 + kb);
                bfrag ap = *(const bfrag*)(ps + (mt * 16 + l16) * 264 + kb);
                qa[mt] = __builtin_amdgcn_mfma_f32_16x16x32_bf16(am, bz, qa[mt], 0, 0, 0);
                wa[mt] = __builtin_amdgcn_mfma_f32_16x16x32_bf16(ap, bw, wa[mt], 0, 0, 0);
            }
        }
        const int col = wave * 16 + l16;
#pragma unroll
        for (int mt = 0; mt < 4; mt++)
#pragma unroll
            for (int r = 0; r < 4; r++) {
                int node = nodeBase + mt * 16 + quad * 4 + r;
                if (node < NN) {
                    qbf[(size_t)node * FS + col] = f2bf(qa[mt][r]);
                    pw2o[(size_t)node * FS + col] = wa[mt][r];
                }
            }
    }
}

// ---------------- aggregation: zq[i,:] = sum_{e: dst=i} q[src_e,:] (bf16 q, fp32 zq) ----------------
__global__ __launch_bounds__(256) void agg_k(const u32* __restrict__ q2,  // [NN][32] packed bf16 pairs
                                             const int* __restrict__ offsets,
                                             const int* __restrict__ srcs,
                                             float* __restrict__ zq) {
    const int wave = threadIdx.x >> 6;
    const int lane = threadIdx.x & 63;
    const int node = blockIdx.x * 4 + wave;
    const int half = lane >> 5, c = lane & 31;
    const int beg = offsets[node], end = offsets[node + 1];
    float ax = 0.f, ay = 0.f;
    int e = beg + half;
    for (; e + 2 < end; e += 4) {
        u32 g0 = q2[(size_t)srcs[e] * 32 + c];
        u32 g1 = q2[(size_t)srcs[e + 2] * 32 + c];
        ax += bf2f((u16)g0) + bf2f((u16)g1);
        ay += bf2f((u16)(g0 >> 16)) + bf2f((u16)(g1 >> 16));
    }
    for (; e < end; e += 2) {
        u32 g = q2[(size_t)srcs[e] * 32 + c];
        ax += bf2f((u16)g);
        ay += bf2f((u16)(g >> 16));
    }
    ax += __shfl_xor(ax, 32);
    ay += __shfl_xor(ay, 32);
    if (half == 0) {
        *(float2*)&zq[(size_t)node * FS + 2 * c] = make_float2(ax, ay);
    }
}

// ---------------- final: out = zq + pw2 + b_post (fp32 elementwise) ----------------
__global__ void final_out_k(const float4* __restrict__ zq, const float4* __restrict__ pw2,
                            const float* __restrict__ b_post, float4* __restrict__ out, int n4) {
    int i = blockIdx.x * 256 + threadIdx.x;
    if (i < n4) {
        float4 z = zq[i], p = pw2[i];
        const float4 b = *(const float4*)(b_post + (i & 15) * 4);
        out[i] = make_float4(z.x + p.x + b.x, z.y + p.y + b.y, z.z + p.z + b.z, z.w + p.w + b.w);
    }
}

extern "C" void kernel_launch(void* const* d_in, const int* in_sizes, int n_in,
                              void* d_out, int out_size, void* d_ws, size_t ws_size,
                              hipStream_t stream) {
    const float* x      = (const float*)d_in[0];
    const int*   ei     = (const int*)d_in[1];
    const float* W_pre  = (const float*)d_in[2];
    const float* b_pre  = (const float*)d_in[3];
    const float* W_conv = (const float*)d_in[4];
    const float* b_conv = (const float*)d_in[5];
    const float* W_post = (const float*)d_in[6];
    const float* b_post = (const float*)d_in[7];
    float* out = (float*)d_out;

    char* ws = (char*)d_ws;
    size_t off = 0;
    auto alloc = [&](size_t bytes) -> char* {
        char* r = ws + off;
        off += (bytes + 255) & ~(size_t)255;
        return r;
    };
    u16* hbf     = (u16*)alloc((size_t)NPAD * FS * 2);    // 12.8 MB
    u16* qbf     = (u16*)alloc((size_t)NN * FS * 2);      // 12.8 MB
    float* zq    = (float*)alloc((size_t)NPAD * FS * 4);  // 25.6 MB
    float* pw2   = (float*)alloc((size_t)NPAD * FS * 4);  // 25.6 MB
    uint2* tmp   = (uint2*)alloc((size_t)NE * 8);         // 12.8 MB
    int* offsets = (int*)alloc((size_t)(NN + 1) * 4);
    int* cnt     = (int*)alloc((size_t)NN * 4);
    int* srcs    = (int*)alloc((size_t)NE * 4);           //  6.4 MB
    int* sums    = (int*)alloc(128 * 4);
    int* cntM    = (int*)alloc((size_t)NBK2 * GA * 4);    // 100 KB
    int* offM    = (int*)alloc((size_t)NBK2 * GA * 4);    // 100 KB
    u16* Wpt     = (u16*)alloc((size_t)HH * FS * 2);      // [256][64]
    u16* Wct     = (u16*)alloc((size_t)HH * HH * 2);      // [256][256]
    u16* Wzt     = (u16*)alloc((size_t)FS * HH * 2);      // [64][256]
    u16* Wp2t    = (u16*)alloc((size_t)FS * HH * 2);      // [64][256]
    (void)ws_size; (void)in_sizes; (void)n_in; (void)out_size;

    const int* dst = ei;       // edge_index[0] = aggregation targets
    const int* src = ei + NE;  // edge_index[1] = message sources

    // input casts / weight transposes
    cvt_x_k<<<(NN * FS / 4 + 255) / 256, 256, 0, stream>>>((const float4*)x, (uint2*)hbf, NN * FS / 4);
    transpose_cvt_k<6, 8><<<(HH * FS + 255) / 256, 256, 0, stream>>>(W_pre, Wpt);
    transpose_cvt_k<8, 8><<<(HH * HH + 255) / 256, 256, 0, stream>>>(W_conv, Wct);
    transpose_cvt_k<8, 6><<<(HH * FS + 255) / 256, 256, 0, stream>>>(W_post, Wzt);
    transpose_cvt_k<8, 6><<<(HH * FS + 255) / 256, 256, 0, stream>>>(W_post + HH * FS, Wp2t);

    // offsets (per-node histogram + hierarchical scan)
    zero_int_k<<<(NN + 255) / 256, 256, 0, stream>>>(cnt, NN);
    hist_k<<<(NE + 255) / 256, 256, 0, stream>>>(dst, cnt);
    const int NB = (NN + 1023) / 1024;  // 98
    scan1_k<<<NB, 256, 0, stream>>>(cnt, offsets, sums);
    scan2_k<<<1, 128, 0, stream>>>(sums, NB);
    scan3_k<<<(NN + 255) / 256, 256, 0, stream>>>(offsets, sums);
    final_off_k<<<1, 64, 0, stream>>>(offsets);

    // srcs permutation (two-phase local-group scatter)
    fillA_k<<<GA, 256, 0, stream>>>(dst, src, cntM, offM, tmp);
    fillB_k<<<NBK2, 256, 0, stream>>>(tmp, cntM, offM, offsets, srcs);

    const int GB = (NN + 63) / 64;  // 1563
    for (int s = 0; s < NSTEPS; s++) {
        if (s == 0)
            xform_k<true><<<GB, 256, 0, stream>>>(hbf, nullptr, nullptr, b_post,
                                                  Wpt, b_pre, Wct, b_conv, Wzt, Wp2t, qbf, pw2);
        else
            xform_k<false><<<GB, 256, 0, stream>>>(nullptr, zq, pw2, b_post,
                                                   Wpt, b_pre, Wct, b_conv, Wzt, Wp2t, qbf, pw2);
        agg_k<<<NN / 4, 256, 0, stream>>>((const u32*)qbf, offsets, srcs, zq);
    }
    final_out_k<<<(NN * 16 + 255) / 256, 256, 0, stream>>>((const float4*)zq, (const float4*)pw2,
                                                           b_post, (float4*)out, NN * 16);
}